// Round 1
// 12259.116 us; speedup vs baseline: 1.2186x; 1.2186x over previous
//
#include <hip/hip_runtime.h>
#include <math.h>

#define BB 8
#define NN 4096
#define DD 512
#define KK 512
#define MAXIT 10

__device__ __forceinline__ float mish_f(float x) {
  float sp = (x > 20.f) ? x : log1pf(expf(x));
  return x * tanhf(sp);
}

// monotonic float -> uint key (for packed u64 atomicMin argmin)
__device__ __forceinline__ unsigned int fkey(float f) {
  unsigned int u = __float_as_uint(f);
  return (u & 0x80000000u) ? ~u : (u | 0x80000000u);
}

// ---------------- transpose 512x512 (W -> Wt) ----------------
__global__ void transpose512(const float* __restrict__ W, float* __restrict__ Wt) {
  __shared__ float tile[32][33];
  int bx = blockIdx.x, by = blockIdx.y;
  int tx = threadIdx.x, ty = threadIdx.y;
  tile[ty][tx] = W[(by*32+ty)*512 + bx*32+tx];
  __syncthreads();
  Wt[(bx*32+ty)*512 + by*32+tx] = tile[tx][ty];
}

// ---------------- centers init: centers = X[:512], c2 = ||c||^2 ----------------
__global__ void init_centers(const float* __restrict__ X, float* __restrict__ centers,
                             float* __restrict__ c2) {
  int k = blockIdx.x, b = blockIdx.y, l = threadIdx.x; // 64 threads
  const float4* src = (const float4*)(X + ((size_t)b*NN + k)*DD) + l*2;
  float4* dst = (float4*)(centers + ((size_t)b*KK + k)*DD) + l*2;
  float4 a0 = src[0], a1 = src[1];
  dst[0] = a0; dst[1] = a1;
  float s = a0.x*a0.x + a0.y*a0.y + a0.z*a0.z + a0.w*a0.w
          + a1.x*a1.x + a1.y*a1.y + a1.z*a1.z + a1.w*a1.w;
  #pragma unroll
  for (int m = 32; m >= 1; m >>= 1) s += __shfl_xor(s, m);
  if (l == 0) c2[b*KK + k] = s;
}

// ---------------- GEMM core: S[i][n] = sum_k A[b][i][k] * Bmat[b][n][k] ----------------
// Block tile 256 rows x 128 cols, per-thread 16x8, K-panel 32.
// Grid: (M/256, N/128, B).
// EPI 0: packed[row] = atomicMin over (key(dist)<<32 | col)  (k-means argmin)
// EPI 1: Gt[b][n][i] = S                                      (transposed store)
// EPI 2: pooled[b][n] += sum_i mish(S + bias[n])
template<int EPI>
__global__ __launch_bounds__(256, 2)
void gemm_bt(const float* __restrict__ A, const float* __restrict__ Bmat,
             int Kd, long long sA, long long sB,
             const float* __restrict__ c2, unsigned long long* __restrict__ packed,
             float* __restrict__ Gt,
             const float* __restrict__ bias, float* __restrict__ pooled)
{
  __shared__ float smem[13824];          // 55296 B: As 256x36 | Bs 128x36
  float* As = smem;                      // 9216 floats
  float* Bs = smem + 9216;               // 4608 floats
  const int t = threadIdx.x;
  const int tx = t & 15, ty = t >> 4;    // cols: tx + 16c ; rows: ty + 16r
  const int b = blockIdx.z;
  const int r0 = blockIdx.x * 256;
  const int c0 = blockIdx.y * 128;
  const float* Ab = A + (size_t)b * sA;
  const float* Bb = Bmat + (size_t)b * sB;

  float acc[16][8];
  #pragma unroll
  for (int r = 0; r < 16; ++r)
    #pragma unroll
    for (int c = 0; c < 8; ++c) acc[r][c] = 0.f;

  for (int k0 = 0; k0 < Kd; k0 += 32) {
    __syncthreads();
    #pragma unroll
    for (int s = 0; s < 8; ++s) {        // stage A: 256 rows x 32 k
      int f = t + s*256;
      int row = f >> 3, k4 = (f & 7) << 2;
      *(float4*)&As[row*36 + k4] = *(const float4*)&Ab[(size_t)(r0+row)*Kd + k0 + k4];
    }
    #pragma unroll
    for (int s = 0; s < 4; ++s) {        // stage B: 128 rows x 32 k
      int f = t + s*256;
      int row = f >> 3, k4 = (f & 7) << 2;
      *(float4*)&Bs[row*36 + k4] = *(const float4*)&Bb[(size_t)(c0+row)*Kd + k0 + k4];
    }
    __syncthreads();
    for (int kk = 0; kk < 32; kk += 4) {
      float4 cv[8];
      #pragma unroll
      for (int c = 0; c < 8; ++c) cv[c] = *(const float4*)&Bs[(tx+16*c)*36 + kk];
      #pragma unroll
      for (int rg = 0; rg < 4; ++rg) {
        float4 xv[4];
        #pragma unroll
        for (int q = 0; q < 4; ++q)
          xv[q] = *(const float4*)&As[(ty + 16*(4*rg+q))*36 + kk];
        #pragma unroll
        for (int q = 0; q < 4; ++q) {
          #pragma unroll
          for (int c = 0; c < 8; ++c) {
            float a = acc[4*rg+q][c];
            a = fmaf(xv[q].x, cv[c].x, a);
            a = fmaf(xv[q].y, cv[c].y, a);
            a = fmaf(xv[q].z, cv[c].z, a);
            a = fmaf(xv[q].w, cv[c].w, a);
            acc[4*rg+q][c] = a;
          }
        }
      }
    }
  }

  if (EPI == 0) {
    float c2v[8];
    #pragma unroll
    for (int c = 0; c < 8; ++c) c2v[c] = c2[b*KK + c0 + tx + 16*c];
    #pragma unroll
    for (int r = 0; r < 16; ++r) {
      float bd = 3.4e38f; int bk = 0;
      #pragma unroll
      for (int c = 0; c < 8; ++c) {      // ascending col order: ties keep lowest col
        float d = fmaf(-2.f, acc[r][c], c2v[c]);
        int col = c0 + tx + 16*c;
        if (d < bd) { bd = d; bk = col; }
      }
      #pragma unroll
      for (int m = 1; m <= 8; m <<= 1) { // reduce across the 16 tx-lanes of this row
        float d2 = __shfl_xor(bd, m); int k2 = __shfl_xor(bk, m);
        if (d2 < bd || (d2 == bd && k2 < bk)) { bd = d2; bk = k2; }
      }
      if (tx == 0) {
        unsigned long long key = ((unsigned long long)fkey(bd) << 32) | (unsigned int)bk;
        atomicMin(&packed[(size_t)b*NN + r0 + ty + 16*r], key);
      }
    }
  } else if (EPI == 1) {
    #pragma unroll
    for (int rh = 0; rh < 4; ++rh) {     // transpose 64-row chunks via LDS
      __syncthreads();
      #pragma unroll
      for (int q = 0; q < 4; ++q)
        #pragma unroll
        for (int c = 0; c < 8; ++c)
          smem[(tx+16*c)*68 + ty + 16*q] = acc[4*rh+q][c];
      __syncthreads();
      #pragma unroll
      for (int s = 0; s < 8; ++s) {
        int f = t + s*256;
        int col = f >> 4, r4 = (f & 15) << 2;
        float4 v;
        v.x = smem[col*68 + r4+0]; v.y = smem[col*68 + r4+1];
        v.z = smem[col*68 + r4+2]; v.w = smem[col*68 + r4+3];
        *(float4*)&Gt[((size_t)b*KK + c0+col)*NN + r0 + rh*64 + r4] = v;
      }
    }
  } else {
    float rs[8];
    #pragma unroll
    for (int c = 0; c < 8; ++c) {
      float bv = bias[c0 + tx + 16*c];
      float s = 0.f;
      #pragma unroll
      for (int r = 0; r < 16; ++r) s += mish_f(acc[r][c] + bv);
      rs[c] = s;
    }
    __syncthreads();
    #pragma unroll
    for (int c = 0; c < 8; ++c) smem[ty*128 + tx + 16*c] = rs[c];
    __syncthreads();
    if (t < 128) {
      float s = 0.f;
      #pragma unroll
      for (int g = 0; g < 16; ++g) s += smem[g*128 + t];
      atomicAdd(&pooled[b*KK + c0 + t], s);
    }
  }
}

// ---------------- membership lists: counts/offsets/members per batch ----------------
// Reads labels from low 32 bits of packed; re-arms packed to ~0 for next iteration.
__global__ void build_members(unsigned long long* __restrict__ packed, int* __restrict__ counts,
                              int* __restrict__ offsets, int* __restrict__ members) {
  __shared__ int cnt[KK];
  __shared__ int scan[KK];
  __shared__ int cur[KK];
  int b = blockIdx.x, t = threadIdx.x;   // 1024 threads
  if (t < KK) cnt[t] = 0;
  __syncthreads();
  for (int i = t; i < NN; i += 1024)
    atomicAdd(&cnt[(int)(packed[(size_t)b*NN + i] & 0xffffffffull)], 1);
  __syncthreads();
  if (t < KK) scan[t] = cnt[t];
  __syncthreads();
  for (int s = 1; s < KK; s <<= 1) {
    int v = 0;
    if (t < KK && t >= s) v = scan[t - s];
    __syncthreads();
    if (t < KK && t >= s) scan[t] += v;
    __syncthreads();
  }
  if (t < KK) {
    int off = scan[t] - cnt[t];
    counts[b*KK + t] = cnt[t];
    offsets[b*KK + t] = off;
    cur[t] = off;
  }
  __syncthreads();
  for (int i = t; i < NN; i += 1024) {
    int lab = (int)(packed[(size_t)b*NN + i] & 0xffffffffull);
    int p = atomicAdd(&cur[lab], 1);
    members[b*NN + p] = i;
    packed[(size_t)b*NN + i] = ~0ull;    // re-init for next gemm_bt<0>
  }
}

// ---------------- center update: mean of member rows (+ new c2) ----------------
__global__ void update_centers(const float* __restrict__ X, const int* __restrict__ counts,
                               const int* __restrict__ offsets, const int* __restrict__ members,
                               float* __restrict__ centers, float* __restrict__ c2) {
  int k = blockIdx.x, b = blockIdx.y, l = threadIdx.x; // 64 threads
  int cnt = counts[b*KK + k];
  if (cnt == 0) return;                 // keep old center, c2 unchanged
  int off = offsets[b*KK + k];
  const float* Xb = X + (size_t)b*NN*DD;
  float4 a0 = {0,0,0,0}, a1 = {0,0,0,0};
  for (int m = 0; m < cnt; ++m) {
    int i = members[b*NN + off + m];
    const float4* r = (const float4*)(Xb + (size_t)i*DD) + l*2;
    float4 v0 = r[0], v1 = r[1];
    a0.x+=v0.x; a0.y+=v0.y; a0.z+=v0.z; a0.w+=v0.w;
    a1.x+=v1.x; a1.y+=v1.y; a1.z+=v1.z; a1.w+=v1.w;
  }
  float fc = (float)cnt;
  a0.x/=fc; a0.y/=fc; a0.z/=fc; a0.w/=fc;
  a1.x/=fc; a1.y/=fc; a1.z/=fc; a1.w/=fc;
  float4* dst = (float4*)(centers + ((size_t)b*KK + k)*DD) + l*2;
  dst[0] = a0; dst[1] = a1;
  float s = a0.x*a0.x+a0.y*a0.y+a0.z*a0.z+a0.w*a0.w
          + a1.x*a1.x+a1.y*a1.y+a1.z*a1.z+a1.w*a1.w;
  #pragma unroll
  for (int m = 32; m >= 1; m >>= 1) s += __shfl_xor(s, m);
  if (l == 0) c2[b*KK + k] = s;
}

// ---------------- h = mish(adj @ one_hot(labels)) via per-row cluster gather ----------------
__global__ void gather_mish(const float* __restrict__ adj, const int* __restrict__ counts,
                            const int* __restrict__ offsets, const int* __restrict__ members,
                            float* __restrict__ hout) {
  __shared__ float row[NN];
  int i = blockIdx.x, b = blockIdx.y, t = threadIdx.x;  // 256 threads
  const float4* ar = (const float4*)(adj + ((size_t)b*NN + i)*NN);
  #pragma unroll
  for (int s = 0; s < 4; ++s) {
    int f = t + s*256;
    *(float4*)&row[4*f] = ar[f];
  }
  __syncthreads();
  #pragma unroll
  for (int h = 0; h < 2; ++h) {
    int k = t + h*256;
    int cnt = counts[b*KK + k];
    int off = offsets[b*KK + k];
    float s = 0.f;
    for (int m = 0; m < cnt; ++m) s += row[members[b*NN + off + m]];
    hout[((size_t)b*NN + i)*DD + k] = mish_f(s);
  }
}

// ---------------- out = pooled @ Wp + bp ----------------
__global__ void final_out(const float* __restrict__ pooled, const float* __restrict__ Wp,
                          const float* __restrict__ bp, float* __restrict__ out) {
  int b = blockIdx.x, l = threadIdx.x;  // 64 threads
  float acc[10];
  #pragma unroll
  for (int o = 0; o < 10; ++o) acc[o] = 0.f;
  for (int k = l; k < 512; k += 64) {
    float p = pooled[b*512 + k];
    #pragma unroll
    for (int o = 0; o < 10; ++o) acc[o] = fmaf(p, Wp[k*10+o], acc[o]);
  }
  #pragma unroll
  for (int o = 0; o < 10; ++o) {
    float s = acc[o];
    #pragma unroll
    for (int m = 32; m >= 1; m >>= 1) s += __shfl_xor(s, m);
    if (l == 0) out[b*10+o] = s + bp[o];
  }
}

extern "C" void kernel_launch(void* const* d_in, const int* in_sizes, int n_in,
                              void* d_out, int out_size, void* d_ws, size_t ws_size,
                              hipStream_t stream) {
  const float* x    = (const float*)d_in[0];
  const float* adj  = (const float*)d_in[1];
  const float* W    = (const float*)d_in[2];
  const float* bias = (const float*)d_in[3];
  const float* Wp   = (const float*)d_in[4];
  const float* bp   = (const float*)d_in[5];
  float* out = (float*)d_out;

  char* ws = (char*)d_ws;
  size_t off = 0;
  auto alloc = [&](size_t bytes) {
    void* p = ws + off;
    off += (bytes + 255) & ~(size_t)255;
    return p;
  };
  float* hbuf    = (float*)alloc((size_t)BB*NN*DD*4);   // 64 MB
  float* Gt      = (float*)alloc((size_t)BB*DD*NN*4);   // 64 MB
  float* centers = (float*)alloc((size_t)BB*KK*DD*4);   // 8 MB
  float* c2      = (float*)alloc((size_t)BB*KK*4);
  unsigned long long* packed = (unsigned long long*)alloc((size_t)BB*NN*8);
  int*   counts  = (int*)alloc((size_t)BB*KK*4);
  int*   offsets = (int*)alloc((size_t)BB*KK*4);
  int*   members = (int*)alloc((size_t)BB*NN*4);
  float* pooled  = (float*)alloc((size_t)BB*DD*4);
  float* Wt      = (float*)alloc((size_t)DD*DD*4);      // 1 MB

  transpose512<<<dim3(16,16), dim3(32,32), 0, stream>>>(W, Wt);
  hipMemsetAsync(packed, 0xFF, (size_t)BB*NN*8, stream);  // arm argmin keys once

  const float* Xcur = x;
  for (int layer = 0; layer < 3; ++layer) {
    init_centers<<<dim3(KK,BB), dim3(64), 0, stream>>>(Xcur, centers, c2);
    for (int it = 0; it < MAXIT; ++it) {
      gemm_bt<0><<<dim3(16,4,BB), dim3(256), 0, stream>>>(
          Xcur, centers, DD, (long long)NN*DD, (long long)KK*DD,
          c2, packed, nullptr, nullptr, nullptr);
      build_members<<<dim3(BB), dim3(1024), 0, stream>>>(packed, counts, offsets, members);
      if (it < MAXIT-1)
        update_centers<<<dim3(KK,BB), dim3(64), 0, stream>>>(
            Xcur, counts, offsets, members, centers, c2);
    }
    gather_mish<<<dim3(NN,BB), dim3(256), 0, stream>>>(adj, counts, offsets, members, hbuf);
    Xcur = hbuf;
  }

  // Gt = (h3 @ W)^T   (Bmat = Wt, shared across batches -> stride 0)
  gemm_bt<1><<<dim3(16,4,BB), dim3(256), 0, stream>>>(
      Xcur, Wt, DD, (long long)NN*DD, 0LL,
      nullptr, nullptr, Gt, nullptr, nullptr);

  hipMemsetAsync(pooled, 0, (size_t)BB*DD*4, stream);

  // pooled[b][k] = sum_i mish( (adj @ G)[i][k] + bias[k] )
  gemm_bt<2><<<dim3(16,4,BB), dim3(256), 0, stream>>>(
      adj, Gt, NN, (long long)NN*NN, (long long)DD*NN,
      nullptr, nullptr, nullptr, bias, pooled);

  final_out<<<dim3(BB), dim3(64), 0, stream>>>(pooled, Wp, bp, out);
}